// Round 6
// baseline (437.581 us; speedup 1.0000x reference)
//
#include <hip/hip_runtime.h>
#include <math.h>

#define B_   16
#define S_   8192
#define KVD  512
#define E_   512
#define H_   8
#define D_   64

// ws float layout (contiguous zero region after qk_vec)
#define OFF_QKVEC   0         // 65536  qk_vec[b][h][c]
#define OFF_LACC    65536     // 128    l_acc[b][h]
#define OFF_CTXACC  65664     // 65536  ctx_acc[b][h][c] (unnormalized)
#define OFF_CTXBUF  131200    // 8192   ctx_buf[b][e]
#define ZERO_START  OFF_LACC
#define ZERO_COUNT  73856     // l_acc + ctx_acc + ctx_buf

// ---------------------------------------------------------------------------
// k_prep: blocks [0,64): fold q through Wk -> qk_vec (each block recomputes
// its q slice; bk dropped: softmax-invariant). blocks [64,145): zero
// accumulators + d_out.
// ---------------------------------------------------------------------------
__global__ __launch_bounds__(256) void k_prep(const float* __restrict__ query,
                                              const float* __restrict__ Wq,
                                              const float* __restrict__ bq,
                                              const float* __restrict__ Wk,
                                              float* __restrict__ wsf,
                                              float* __restrict__ out) {
    const int blk = blockIdx.x;
    const int tid = threadIdx.x;

    if (blk >= 64) {
        int i = (blk - 64) * 256 + tid;  // float4 index
        const int nws4 = ZERO_COUNT / 4; // 18464
        if (i < nws4) {
            *(float4*)&wsf[ZERO_START + i * 4] = make_float4(0.f, 0.f, 0.f, 0.f);
        } else if (i < nws4 + (B_ * E_) / 4) {
            *(float4*)&out[(size_t)(i - nws4) * 4] = make_float4(0.f, 0.f, 0.f, 0.f);
        }
        return;
    }

    const int cc = blk & 7, h = blk >> 3;
    float* qk_vec = wsf + OFF_QKVEC;

    __shared__ float qbuf[16 * 512];   // 32 KB raw query
    __shared__ float wk[64 * 65];      // Wk tile, padded
    __shared__ float qh[16 * 64];      // scaled q slice for head h

    // stage query[16][512] (float4) and Wk[cc*64..+63][h*64..+63]
    #pragma unroll
    for (int k = 0; k < 8; ++k) {
        int f4i = tid + k * 256;       // 2048 float4
        *(float4*)&qbuf[f4i * 4] = *(const float4*)&query[(size_t)f4i * 4];
    }
    #pragma unroll
    for (int k = 0; k < 4; ++k) {
        int f4i = tid + k * 256;       // 1024 float4
        int row = f4i >> 4, d4 = f4i & 15;
        float4 v = *(const float4*)&Wk[(size_t)(cc * 64 + row) * E_ + h * D_ + d4 * 4];
        wk[row * 65 + d4 * 4 + 0] = v.x;
        wk[row * 65 + d4 * 4 + 1] = v.y;
        wk[row * 65 + d4 * 4 + 2] = v.z;
        wk[row * 65 + d4 * 4 + 3] = v.w;
    }
    __syncthreads();

    // phase 1: q[b][h*64+d] for b = w*4..w*4+3, d = lane
    const int d = tid & 63, w = tid >> 6;
    {
        float acc[4] = {0.f, 0.f, 0.f, 0.f};
        const float* wq = Wq + h * D_ + d;
        for (int k = 0; k < 512; k += 4) {
            #pragma unroll
            for (int kk = 0; kk < 4; ++kk) {
                float wv = wq[(size_t)(k + kk) * E_];
                #pragma unroll
                for (int i = 0; i < 4; ++i)
                    acc[i] = fmaf(qbuf[(w * 4 + i) * 512 + k + kk], wv, acc[i]);
            }
        }
        float bqv = bq[h * D_ + d];
        #pragma unroll
        for (int i = 0; i < 4; ++i)
            qh[(w * 4 + i) * 64 + d] = (acc[i] + bqv) * 0.125f;  // 1/sqrt(64)
    }
    __syncthreads();

    // phase 2: qk_vec[b][h][cc*64 + c] = sum_d qh[b][d] * wk[c][d]
    {
        const int c_local = tid & 63;
        float acc[4] = {0.f, 0.f, 0.f, 0.f};
        for (int dd = 0; dd < 64; ++dd) {
            float wv = wk[c_local * 65 + dd];
            #pragma unroll
            for (int i = 0; i < 4; ++i)
                acc[i] = fmaf(qh[(w * 4 + i) * 64 + dd], wv, acc[i]);
        }
        #pragma unroll
        for (int i = 0; i < 4; ++i) {
            int b = w * 4 + i;
            qk_vec[((size_t)b * H_ + h) * KVD + cc * 64 + c_local] = acc[i];
        }
    }
}

// ---------------------------------------------------------------------------
// k_attn v10: 8 waves, ONE head per wave, one softmax chain per tile.
//
// R5 post-mortem: heads-split (2 heads/wave, 4 waves) cut k_attn ~100->83us.
// Remaining cost: 2 serial chains per tile falsely coupled through the shared
// scr region + only 2 waves/SIMD to hide them.
//
// v10: 512-thread blocks (8 waves), each wave owns ONE head; block stages
// 8-row KV tiles (32 KB dbuf, global_load_lds, 1 barrier/tile). Per tile each
// wave: 16 ds_read_b128 (all 8 rows), 64 dot-FMA, 8 scatter writes, ONE
// gather+butterfly+expf chain (lane-group hme owns row hme), 8 broadcast
// shfls, 64 PV-FMA. Half the per-row issue of v9, one chain per tile, and
// __launch_bounds__(512,4) -> 4 waves/SIMD (2 blocks/CU, LDS 49.4 KB) to
// hide it. Heads wave-exclusive -> direct global atomics, no block merge.
// VGPR ~110 (kvr 64 + qk 8 + ctx 8 + temps) under the 128 cap -> no spill.
// ---------------------------------------------------------------------------
#define SROW 68
#define T_   8   // rows per LDS tile

__device__ __forceinline__ void stage_tile8(const float* __restrict__ chunkbase,
                                            int t, float (&buf)[T_][KVD],
                                            int w, int lane) {
    // wave w stages row w of tile t: 2 halves x 1 KB (64 lanes x 16 B)
    const float* rowp = chunkbase + (size_t)(t * T_ + w) * KVD;
    __builtin_amdgcn_global_load_lds(
        (__attribute__((address_space(1))) unsigned int*)(rowp + lane * 4),
        (__attribute__((address_space(3))) unsigned int*)(&buf[w][0]),
        16, 0, 0);
    __builtin_amdgcn_global_load_lds(
        (__attribute__((address_space(1))) unsigned int*)(rowp + 256 + lane * 4),
        (__attribute__((address_space(3))) unsigned int*)(&buf[w][256]),
        16, 0, 0);
}

template <int NC>
__global__ __launch_bounds__(512, 4) void k_attn(const float* __restrict__ kv,
                                                 const float* __restrict__ qk_vec,
                                                 float* __restrict__ ctx_acc,
                                                 float* __restrict__ l_acc) {
    constexpr int CHUNK = S_ / NC;         // NC=32 -> 256 rows/block
    constexpr int NT = CHUNK / T_;         // 32 tiles

    __shared__ __align__(16) float kbuf[2][T_][KVD];  // 32 KB double-buffered tile
    __shared__ __align__(16) float scr[8][T_][SROW];  // 17.4 KB scatter (wave-private)

    const int tid = threadIdx.x;
    const int lane = tid & 63;
    const int w = tid >> 6;                // wave id == head id
    const int nc = blockIdx.x, b = blockIdx.y;
    const int hme = lane >> 3, seg = lane & 7;  // lane-group hme owns row hme

    // wave's head vector (already scaled by 1/8 in k_prep)
    float qk1[8];
    {
        const float* qb = qk_vec + ((size_t)b * H_ + w) * KVD;
        float4 v0 = *(const float4*)&qb[lane * 4];
        float4 v1 = *(const float4*)&qb[256 + lane * 4];
        qk1[0] = v0.x; qk1[1] = v0.y; qk1[2] = v0.z; qk1[3] = v0.w;
        qk1[4] = v1.x; qk1[5] = v1.y; qk1[6] = v1.z; qk1[7] = v1.w;
    }

    float ctx1[8];
    #pragma unroll
    for (int j = 0; j < 8; ++j) ctx1[j] = 0.f;
    float l_loc = 0.f;

    const float* chunkbase = kv + ((size_t)b * S_ + (size_t)nc * CHUNK) * KVD;

    stage_tile8(chunkbase, 0, kbuf[0], w, lane);
    __syncthreads();   // drains vmcnt -> tile 0 resident & visible

    int p = 0;
    #pragma unroll 1
    for (int t = 0; t < NT; ++t) {
        if (t + 1 < NT) stage_tile8(chunkbase, t + 1, kbuf[p ^ 1], w, lane);

        // load all 8 rows of tile into registers
        float kvr[T_][8];
        #pragma unroll
        for (int r = 0; r < T_; ++r) {
            const float* rp = &kbuf[p][r][0];
            float4 v0 = *(const float4*)&rp[lane * 4];
            float4 v1 = *(const float4*)&rp[256 + lane * 4];
            kvr[r][0] = v0.x; kvr[r][1] = v0.y; kvr[r][2] = v0.z; kvr[r][3] = v0.w;
            kvr[r][4] = v1.x; kvr[r][5] = v1.y; kvr[r][6] = v1.z; kvr[r][7] = v1.w;
        }
        // dot partials for wave's head -> scatter (lanes consecutive)
        #pragma unroll
        for (int r = 0; r < T_; ++r) {
            float pp = 0.f;
            #pragma unroll
            for (int j = 0; j < 8; ++j) pp = fmaf(kvr[r][j], qk1[j], pp);
            scr[w][r][lane] = pp;
        }
        asm volatile("" ::: "memory");
        // single chain: lane-group hme gathers row hme's 64 partials
        const float* gp = &scr[w][hme][seg * 8];
        float4 x = *(const float4*)gp;
        float4 y = *(const float4*)(gp + 4);
        float s = ((x.x + x.y) + (x.z + x.w)) + ((y.x + y.y) + (y.z + y.w));
        s += __shfl_xor(s, 1);
        s += __shfl_xor(s, 2);
        s += __shfl_xor(s, 4);
        float e = __expf(s);   // replicated 8x across seg
        l_loc += e;
        // broadcast weights + PV accumulate
        #pragma unroll
        for (int r = 0; r < T_; ++r) {
            float wv = __shfl(e, r * 8 + seg);
            #pragma unroll
            for (int j = 0; j < 8; ++j)
                ctx1[j] = fmaf(wv, kvr[r][j], ctx1[j]);
        }
        __syncthreads();
        p ^= 1;
    }

    // ---- l reduction: all-64-lane sum counts each row's e 8x -> /8
    {
        float ls = l_loc;
        ls += __shfl_xor(ls, 1);
        ls += __shfl_xor(ls, 2);
        ls += __shfl_xor(ls, 4);
        ls += __shfl_xor(ls, 8);
        ls += __shfl_xor(ls, 16);
        ls += __shfl_xor(ls, 32);
        ls *= 0.125f;
        if (lane == 0) atomicAdd(&l_acc[b * H_ + w], ls);
    }

    // ---- ctx: head w exclusive to wave w within block -> direct atomics
    {
        float* dst = &ctx_acc[(size_t)(b * H_ + w) * KVD];
        #pragma unroll
        for (int j = 0; j < 4; ++j)
            atomicAdd(&dst[lane * 4 + j], ctx1[j]);
        #pragma unroll
        for (int j = 4; j < 8; ++j)
            atomicAdd(&dst[256 + lane * 4 + (j - 4)], ctx1[j]);
    }
}

// ---------------------------------------------------------------------------
// k_ctx: ctx_buf[b][e] += (sum_{c chunk} ctx_acc[b,h(e),c]*Wv[c][e]) / l[b,h]
//        (+ bv[e] on kc==0).  grid (kc=4, b=16) x 512
// ---------------------------------------------------------------------------
__global__ __launch_bounds__(512) void k_ctx(const float* __restrict__ ctx_acc,
                                             const float* __restrict__ l_acc,
                                             const float* __restrict__ Wv,
                                             const float* __restrict__ bv,
                                             float* __restrict__ ctx_buf) {
    const int kc = blockIdx.x, b = blockIdx.y;
    const int e = threadIdx.x;
    const int h = e >> 6;
    const float inv = 1.0f / l_acc[b * H_ + h];
    const float* ca = ctx_acc + ((size_t)b * H_ + h) * KVD + kc * 128;
    const float* wv = Wv + (size_t)(kc * 128) * E_ + e;
    float a0 = 0.f, a1 = 0.f, a2 = 0.f, a3 = 0.f;
    for (int c = 0; c < 128; c += 4) {
        a0 = fmaf(ca[c],     wv[(size_t)(c)     * E_], a0);
        a1 = fmaf(ca[c + 1], wv[(size_t)(c + 1) * E_], a1);
        a2 = fmaf(ca[c + 2], wv[(size_t)(c + 2) * E_], a2);
        a3 = fmaf(ca[c + 3], wv[(size_t)(c + 3) * E_], a3);
    }
    float val = ((a0 + a1) + (a2 + a3)) * inv;
    if (kc == 0) val += bv[e];
    atomicAdd(&ctx_buf[(size_t)b * E_ + e], val);
}

// ---------------------------------------------------------------------------
// k_o: out[b][e] += sum_{i chunk} ctx_buf[b][i]*Wo[i][e] (+ bo[e] on kc==0)
// grid (kc=4, b=16) x 512
// ---------------------------------------------------------------------------
__global__ __launch_bounds__(512) void k_o(const float* __restrict__ ctx_buf,
                                           const float* __restrict__ Wo,
                                           const float* __restrict__ bo,
                                           float* __restrict__ out) {
    const int kc = blockIdx.x, b = blockIdx.y;
    const int e = threadIdx.x;
    const float* cs = ctx_buf + (size_t)b * E_ + kc * 128;
    const float* wo = Wo + (size_t)(kc * 128) * E_ + e;
    float a0 = 0.f, a1 = 0.f, a2 = 0.f, a3 = 0.f;
    for (int k = 0; k < 128; k += 4) {
        a0 = fmaf(cs[k],     wo[(size_t)(k)     * E_], a0);
        a1 = fmaf(cs[k + 1], wo[(size_t)(k + 1) * E_], a1);
        a2 = fmaf(cs[k + 2], wo[(size_t)(k + 2) * E_], a2);
        a3 = fmaf(cs[k + 3], wo[(size_t)(k + 3) * E_], a3);
    }
    float val = (a0 + a1) + (a2 + a3);
    if (kc == 0) val += bo[e];
    atomicAdd(&out[(size_t)b * E_ + e], val);
}

// ---------------------------------------------------------------------------
extern "C" void kernel_launch(void* const* d_in, const int* in_sizes, int n_in,
                              void* d_out, int out_size, void* d_ws, size_t ws_size,
                              hipStream_t stream) {
    const float* query = (const float*)d_in[0];
    const float* kv    = (const float*)d_in[1];
    const float* Wq    = (const float*)d_in[2];
    const float* bq    = (const float*)d_in[3];
    const float* Wk    = (const float*)d_in[4];
    // d_in[5] = bk: softmax-invariant per (b,h) -> unused
    const float* Wv    = (const float*)d_in[6];
    const float* bv    = (const float*)d_in[7];
    const float* Wo    = (const float*)d_in[8];
    const float* bo    = (const float*)d_in[9];
    float* out = (float*)d_out;
    float* wsf = (float*)d_ws;

    float* qk_vec  = wsf + OFF_QKVEC;
    float* l_acc   = wsf + OFF_LACC;
    float* ctx_acc = wsf + OFF_CTXACC;
    float* ctx_buf = wsf + OFF_CTXBUF;

    constexpr int NC = 32;  // 512 blocks x 512 threads; 2 blocks/CU, 4 waves/SIMD

    k_prep<<<145, 256, 0, stream>>>(query, Wq, bq, Wk, wsf, out);
    k_attn<NC><<<dim3(NC, B_), 512, 0, stream>>>(kv, qk_vec, ctx_acc, l_acc);
    k_ctx<<<dim3(4, B_), 512, 0, stream>>>(ctx_acc, l_acc, Wv, bv, ctx_buf);
    k_o<<<dim3(4, B_), 512, 0, stream>>>(ctx_buf, Wo, bo, out);
}